// Round 6
// baseline (241.766 us; speedup 1.0000x reference)
//
#include <hip/hip_runtime.h>

#define FDIM 128
#define BIN_CAP 500          // per (partition,group) staging capacity; mean 256, sigma 16

typedef __attribute__((ext_vector_type(4))) float f32x4;
typedef __attribute__((ext_vector_type(8))) short s16x8;
typedef __attribute__((ext_vector_type(4))) short s16x4;

__device__ inline unsigned short f2bf(float f) {      // RNE f32->bf16
    unsigned u = __builtin_bit_cast(unsigned, f);
    u += 0x7FFFu + ((u >> 16) & 1u);
    return (unsigned short)(u >> 16);
}
__device__ inline float bflo(unsigned u) { return __builtin_bit_cast(float, u << 16); }
__device__ inline float bfhi(unsigned u) { return __builtin_bit_cast(float, u & 0xFFFF0000u); }

// ======================= CSR build =======================
__global__ void hist_kernel(const int* __restrict__ dst, int* __restrict__ deg, int E) {
    int e = blockIdx.x * blockDim.x + threadIdx.x;
    if (e < E) atomicAdd(&deg[dst[e]], 1);
}

__global__ void scan1_kernel(const int* __restrict__ deg, int* __restrict__ rp,
                             int* __restrict__ bsum, int N) {
    __shared__ int s[256];
    int i = blockIdx.x * 256 + threadIdx.x;
    int v = (i < N) ? deg[i] : 0;
    s[threadIdx.x] = v;
    __syncthreads();
    for (int off = 1; off < 256; off <<= 1) {
        int t = (threadIdx.x >= off) ? s[threadIdx.x - off] : 0;
        __syncthreads();
        s[threadIdx.x] += t;
        __syncthreads();
    }
    if (i < N) rp[i] = s[threadIdx.x] - v;
    if (threadIdx.x == 255) bsum[blockIdx.x] = s[255];
}

__global__ void scan2_kernel(int* __restrict__ bsum, int nb) {
    __shared__ int s[256];
    int v = (threadIdx.x < (unsigned)nb) ? bsum[threadIdx.x] : 0;
    s[threadIdx.x] = v;
    __syncthreads();
    for (int off = 1; off < 256; off <<= 1) {
        int t = (threadIdx.x >= off) ? s[threadIdx.x - off] : 0;
        __syncthreads();
        s[threadIdx.x] += t;
        __syncthreads();
    }
    if (threadIdx.x < (unsigned)nb) bsum[threadIdx.x] = s[threadIdx.x] - v;
}

__global__ void scan3_kernel(int* __restrict__ rp, const int* __restrict__ bsum,
                             int* __restrict__ cursor, int N, int E) {
    int i = blockIdx.x * 256 + threadIdx.x;
    if (i < N) {
        int v = rp[i] + bsum[blockIdx.x];
        rp[i] = v;
        cursor[i] = v;
    } else if (i == N) {
        rp[N] = E;
    }
}

// -------- binned fill: pass A — append (src,dst) into (dst>>7, blk&7) staging bins.
// Dense per-bin appends -> coalesced line usage; one group ~ one XCD (heuristic only).
// Overflow (never expected at CAP=500) falls back to direct global-cursor placement.
__global__ void binA_kernel(const int* __restrict__ src, const int* __restrict__ dst,
                            int* __restrict__ pcur, int2* __restrict__ stag,
                            int* __restrict__ cursor, int* __restrict__ eid, int E) {
    int e = blockIdx.x * blockDim.x + threadIdx.x;
    if (e >= E) return;
    int d = dst[e], s = src[e];
    int bin = (d >> 7) * 8 + (blockIdx.x & 7);
    int slot = atomicAdd(&pcur[bin], 1);
    if (slot < BIN_CAP) {
        stag[(size_t)bin * BIN_CAP + slot] = make_int2(s, d);
    } else {
        int p = atomicAdd(&cursor[d], 1);   // slow path, correctness guard
        eid[p] = s;
    }
}

// -------- binned fill: pass B — one block per partition (128 nodes); LDS cursors
// seeded from global cursor (includes any slow-path placements). eid writes land
// in the partition's ~8KB contiguous range.
__global__ void binB_kernel(const int* __restrict__ pcur, const int2* __restrict__ stag,
                            const int* __restrict__ cursor, int* __restrict__ eid, int N) {
    __shared__ int lcur[128];
    int part = blockIdx.x;
    int node0 = part << 7;
    if (threadIdx.x < 128) {
        int node = node0 + threadIdx.x;
        lcur[threadIdx.x] = (node < N) ? cursor[node] : 0;
    }
    __syncthreads();
#pragma unroll
    for (int g = 0; g < 8; ++g) {
        int bin = part * 8 + g;
        int cnt = min(pcur[bin], BIN_CAP);
        const int2* base = stag + (size_t)bin * BIN_CAP;
        for (int i = threadIdx.x; i < cnt; i += 256) {
            int2 sd = base[i];
            int p = atomicAdd(&lcur[sd.y & 127], 1);
            eid[p] = sd.x;
        }
    }
}

// ======================= bf16 prep =======================
__global__ void prep_x_kernel(const float* __restrict__ x, short* __restrict__ xb, int n4) {
    int i = blockIdx.x * blockDim.x + threadIdx.x;
    if (i < n4) {
        float4 v = reinterpret_cast<const float4*>(x)[i];
        s16x4 o;
        o[0] = (short)f2bf(v.x); o[1] = (short)f2bf(v.y);
        o[2] = (short)f2bf(v.z); o[3] = (short)f2bf(v.w);
        reinterpret_cast<s16x4*>(xb)[i] = o;
    }
}

__global__ void prep_w_kernel(const float* __restrict__ Wl0, const float* __restrict__ Wr0,
                              const float* __restrict__ Wl1, const float* __restrict__ Wr1,
                              short* __restrict__ Wt0, short* __restrict__ Wt1) {
    int g = blockIdx.x * blockDim.x + threadIdx.x;   // [0, 65536)
    int n = g & 127;
    int k = (g >> 7) & 255;
    int layer = g >> 15;
    const float* Wl = layer ? Wl1 : Wl0;
    const float* Wr = layer ? Wr1 : Wr0;
    short* Wt = layer ? Wt1 : Wt0;
    float v = (k < 128) ? Wl[k * 128 + n] : Wr[(k - 128) * 128 + n];
    Wt[n * 256 + k] = (short)f2bf(v);
}

// ============ mean-aggregate via gather (bf16 in/out, fp32 accum) ============
// One wave per node; lane l covers cols {2l, 2l+1}; 8-deep unroll for MLP.
__global__ void gather_kernel(const short* __restrict__ xb, const int* __restrict__ rp,
                              const int* __restrict__ eid, short* __restrict__ mb, int N) {
    int node = blockIdx.x * (blockDim.x >> 6) + (threadIdx.x >> 6);
    int lane = threadIdx.x & 63;
    if (node >= N) return;
    int beg = rp[node], end = rp[node + 1];
    float ax = 0.f, ay = 0.f;
    int k = beg;
    for (; k + 8 <= end; k += 8) {
        unsigned u[8];
#pragma unroll
        for (int q = 0; q < 8; ++q) {
            int s = eid[k + q];
            u[q] = reinterpret_cast<const unsigned*>(xb + (size_t)s * FDIM)[lane];
        }
#pragma unroll
        for (int q = 0; q < 8; ++q) { ax += bflo(u[q]); ay += bfhi(u[q]); }
    }
    for (; k + 2 <= end; k += 2) {
        int s0 = eid[k], s1 = eid[k + 1];
        unsigned u0 = reinterpret_cast<const unsigned*>(xb + (size_t)s0 * FDIM)[lane];
        unsigned u1 = reinterpret_cast<const unsigned*>(xb + (size_t)s1 * FDIM)[lane];
        ax += bflo(u0) + bflo(u1);
        ay += bfhi(u0) + bfhi(u1);
    }
    for (; k < end; ++k) {
        int s = eid[k];
        unsigned u = reinterpret_cast<const unsigned*>(xb + (size_t)s * FDIM)[lane];
        ax += bflo(u);
        ay += bfhi(u);
    }
    float inv = (end > beg) ? 1.0f / (float)(end - beg) : 0.0f;
    unsigned lo = f2bf(ax * inv), hi = f2bf(ay * inv);
    reinterpret_cast<unsigned*>(mb + (size_t)node * FDIM)[lane] = lo | (hi << 16);
}

// ===================== MFMA GEMM: out = [mean|x] @ [Wl;Wr] + b (R4-proven) ============
template <bool RELU, bool OUTF32>
__global__ __launch_bounds__(256, 2)
void gemm_mfma_kernel(const short* __restrict__ Am, const short* Ax,
                      const short* __restrict__ Wt, const float* __restrict__ bias,
                      float* outf, short* outb, int n) {
    __shared__ short A_lds[64 * 256];   // 32 KB
    const int tid = threadIdx.x;
    const int w = tid >> 6, l = tid & 63;
    const int row0 = blockIdx.x * 64;

    s16x8 bfr[8][2];
    {
        const short* wb = Wt + ((32 * w + (l & 15)) * 256 + 8 * (l >> 4));
#pragma unroll
        for (int kc = 0; kc < 8; ++kc)
#pragma unroll
            for (int cf = 0; cf < 2; ++cf)
                bfr[kc][cf] = *reinterpret_cast<const s16x8*>(wb + cf * 16 * 256 + kc * 32);
    }

#pragma unroll
    for (int i = 0; i < 8; ++i) {
        int c = tid + 256 * i;          // [0, 2048)
        int r = c >> 5;
        int ck = c & 31;
        int row = row0 + r;
        s16x8 v;
        if (row < n) {
            const short* sp = (ck < 16) ? (Am + (size_t)row * FDIM + ck * 8)
                                        : (Ax + (size_t)row * FDIM + (ck - 16) * 8);
            v = *reinterpret_cast<const s16x8*>(sp);
        } else {
#pragma unroll
            for (int j = 0; j < 8; ++j) v[j] = 0;
        }
        int byte = r * 512 + ((ck * 16) ^ ((r & 7) << 4));
        *reinterpret_cast<s16x8*>(reinterpret_cast<char*>(A_lds) + byte) = v;
    }
    __syncthreads();

    f32x4 acc[4][2];
    {
        float b0 = bias[32 * w + (l & 15)];
        float b1 = bias[32 * w + 16 + (l & 15)];
#pragma unroll
        for (int rf = 0; rf < 4; ++rf)
#pragma unroll
            for (int i = 0; i < 4; ++i) { acc[rf][0][i] = b0; acc[rf][1][i] = b1; }
    }

    const int arow = l & 15;
    const int aq16 = 16 * (l >> 4);
#pragma unroll
    for (int kc = 0; kc < 8; ++kc) {
        s16x8 afr[4];
#pragma unroll
        for (int rf = 0; rf < 4; ++rf) {
            int r = 16 * rf + arow;
            int kbyte = 64 * kc + aq16;
            int byte = r * 512 + (kbyte ^ ((r & 7) << 4));
            afr[rf] = *reinterpret_cast<const s16x8*>(reinterpret_cast<const char*>(A_lds) + byte);
        }
#pragma unroll
        for (int rf = 0; rf < 4; ++rf)
#pragma unroll
            for (int cf = 0; cf < 2; ++cf)
                acc[rf][cf] = __builtin_amdgcn_mfma_f32_16x16x32_bf16(afr[rf], bfr[kc][cf], acc[rf][cf], 0, 0, 0);
    }

    const int ocol = 32 * w + (l & 15);
    const int orow = 4 * (l >> 4);
#pragma unroll
    for (int rf = 0; rf < 4; ++rf)
#pragma unroll
        for (int cf = 0; cf < 2; ++cf)
#pragma unroll
            for (int i = 0; i < 4; ++i) {
                int row = row0 + 16 * rf + orow + i;
                if (row < n) {
                    float v = acc[rf][cf][i];
                    if (RELU) v = fmaxf(v, 0.0f);
                    if (OUTF32) outf[(size_t)row * FDIM + ocol + 16 * cf] = v;
                    else        outb[(size_t)row * FDIM + ocol + 16 * cf] = (short)f2bf(v);
                }
            }
}

// ===================== fallback: atomic scatter path (R2, proven) =====================
__global__ void degree_kernel(const int* __restrict__ dst, float* __restrict__ cnt, int E) {
    int e = blockIdx.x * blockDim.x + threadIdx.x;
    if (e < E) atomicAdd(&cnt[dst[e]], 1.0f);
}

__global__ void scatter_kernel(const float* __restrict__ x, const int* __restrict__ src,
                               const int* __restrict__ dst, float* __restrict__ msg, int E) {
    int gt = blockIdx.x * blockDim.x + threadIdx.x;
    int e = gt >> 6;
    int lane = gt & 63;
    if (e >= E) return;
    int s = src[e];
    int d = dst[e];
    float2 v = reinterpret_cast<const float2*>(x + (size_t)s * FDIM)[lane];
    float* md = msg + (size_t)d * FDIM + 2 * lane;
    atomicAdd(md, v.x);
    atomicAdd(md + 1, v.y);
}

template <bool RELU>
__global__ void gemm_kernel(const float* agg, const float* cnt,
                            const float* __restrict__ xin, const float* __restrict__ Wl,
                            const float* __restrict__ Wr, const float* __restrict__ bias,
                            float* out, int n) {
    const int ROWS = 16;
    __shared__ float m_s[ROWS][FDIM];
    __shared__ float x_s[ROWS][FDIM];
    int tid = threadIdx.x;
    int row0 = blockIdx.x * ROWS;
#pragma unroll
    for (int i = 0; i < 2; ++i) {
        int idx4 = tid + i * 256;
        int r = idx4 >> 5;
        int c4 = idx4 & 31;
        int row = row0 + r;
        if (row < n) {
            float inv = cnt ? 1.0f / fmaxf(cnt[row], 1.0f) : 1.0f;
            float4 mv = reinterpret_cast<const float4*>(agg + (size_t)row * FDIM)[c4];
            float4 xv = reinterpret_cast<const float4*>(xin + (size_t)row * FDIM)[c4];
            float* mp = &m_s[r][c4 * 4];
            mp[0] = mv.x * inv; mp[1] = mv.y * inv; mp[2] = mv.z * inv; mp[3] = mv.w * inv;
            float* xp = &x_s[r][c4 * 4];
            xp[0] = xv.x; xp[1] = xv.y; xp[2] = xv.z; xp[3] = xv.w;
        }
    }
    __syncthreads();
    int j = tid & 127;
    int rh = tid >> 7;
    float acc[8];
    float bj = bias[j];
#pragma unroll
    for (int r = 0; r < 8; ++r) acc[r] = bj;
#pragma unroll 4
    for (int k = 0; k < FDIM; ++k) {
        float wl = Wl[k * FDIM + j];
        float wr = Wr[k * FDIM + j];
#pragma unroll
        for (int r = 0; r < 8; ++r)
            acc[r] += m_s[rh * 8 + r][k] * wl + x_s[rh * 8 + r][k] * wr;
    }
#pragma unroll
    for (int r = 0; r < 8; ++r) {
        int row = row0 + rh * 8 + r;
        if (row < n) {
            float v = acc[r];
            if (RELU) v = fmaxf(v, 0.0f);
            out[(size_t)row * FDIM + j] = v;
        }
    }
}

extern "C" void kernel_launch(void* const* d_in, const int* in_sizes, int n_in,
                              void* d_out, int out_size, void* d_ws, size_t ws_size,
                              hipStream_t stream) {
    const float* x   = (const float*)d_in[0];
    const int*   ei  = (const int*)d_in[1];
    const float* Wl0 = (const float*)d_in[2];
    const float* Wr0 = (const float*)d_in[3];
    const float* b0  = (const float*)d_in[4];
    const float* Wl1 = (const float*)d_in[5];
    const float* Wr1 = (const float*)d_in[6];
    const float* b1  = (const float*)d_in[7];

    int N = in_sizes[0] / FDIM;   // 50000
    int E = in_sizes[1] / 2;      // 800000
    const int* src = ei;
    const int* dst = ei + E;

    size_t featBytes  = (size_t)N * FDIM * sizeof(float);   // 25.6 MB
    size_t featBytesB = (size_t)N * FDIM * sizeof(short);   // 12.8 MB
    int edgeBlocks = (E + 255) / 256;
    int nb = (N + 255) / 256;
    int npart = (N + 127) >> 7;   // 391

    // workspace layout (same 30,056,448 B footprint as R4)
    const size_t o_deg  = 0;                    // N ints
    const size_t o_rp   = 0x40000;              // N+1 ints
    const size_t o_cur  = 0x80000;              // N ints
    const size_t o_bsum = 0xC0000;              // nb ints
    const size_t o_pcur = 0xC4000;              // npart*8 ints (12.5 KB)
    const size_t o_wt0  = 0xD0000;              // 64 KB
    const size_t o_wt1  = 0xE0000;              // 64 KB
    const size_t o_eid  = 0x100000;             // E ints
    const size_t o_xb   = 0x440000;             // N*128 bf16 (x, then h in-place)
    const size_t o_mb   = o_xb + featBytesB;    // N*128 bf16 (mean) / binned-fill staging
    const size_t need   = o_mb + featBytesB;

    // staging must fit inside the mb region: npart*8*BIN_CAP*8B = 12.51 MB <= 12.8 MB
    bool stag_fits = (size_t)npart * 8 * BIN_CAP * sizeof(int2) <= featBytesB;

    if (ws_size >= need && stag_fits) {
        int*   deg    = (int*)((char*)d_ws + o_deg);
        int*   rp     = (int*)((char*)d_ws + o_rp);
        int*   cursor = (int*)((char*)d_ws + o_cur);
        int*   bsum   = (int*)((char*)d_ws + o_bsum);
        int*   pcur   = (int*)((char*)d_ws + o_pcur);
        short* Wt0    = (short*)((char*)d_ws + o_wt0);
        short* Wt1    = (short*)((char*)d_ws + o_wt1);
        int*   eid    = (int*)((char*)d_ws + o_eid);
        short* xb     = (short*)((char*)d_ws + o_xb);
        short* mb     = (short*)((char*)d_ws + o_mb);
        int2*  stag   = (int2*)((char*)d_ws + o_mb);   // time-shares mb (dead until gather)
        float* outF   = (float*)d_out;

        // CSR build with binned fill
        hipMemsetAsync(deg, 0, (size_t)N * sizeof(int), stream);
        hipMemsetAsync(pcur, 0, (size_t)npart * 8 * sizeof(int), stream);
        hist_kernel<<<edgeBlocks, 256, 0, stream>>>(dst, deg, E);
        scan1_kernel<<<nb, 256, 0, stream>>>(deg, rp, bsum, N);
        scan2_kernel<<<1, 256, 0, stream>>>(bsum, nb);
        scan3_kernel<<<(N + 256) / 256, 256, 0, stream>>>(rp, bsum, cursor, N, E);
        binA_kernel<<<edgeBlocks, 256, 0, stream>>>(src, dst, pcur, stag, cursor, eid, E);
        binB_kernel<<<npart, 256, 0, stream>>>(pcur, stag, cursor, eid, N);

        // bf16 prep
        prep_w_kernel<<<256, 256, 0, stream>>>(Wl0, Wr0, Wl1, Wr1, Wt0, Wt1);
        prep_x_kernel<<<(N * FDIM / 4 + 255) / 256, 256, 0, stream>>>(x, xb, N * FDIM / 4);

        int gatherBlocks = (N + 3) / 4;
        int gemmBlocks   = (N + 63) / 64;
        // layer 0: h(bf16, in-place over xb) = relu([mean|x] @ Wcat0 + b0)
        gather_kernel<<<gatherBlocks, 256, 0, stream>>>(xb, rp, eid, mb, N);
        gemm_mfma_kernel<true, false><<<gemmBlocks, 256, 0, stream>>>(mb, xb, Wt0, b0, nullptr, xb, N);
        // layer 1: out(f32) = [mean(h)|h] @ Wcat1 + b1
        gather_kernel<<<gatherBlocks, 256, 0, stream>>>(xb, rp, eid, mb, N);
        gemm_mfma_kernel<false, true><<<gemmBlocks, 256, 0, stream>>>(mb, xb, Wt1, b1, outF, nullptr, N);
    } else {
        // fallback: proven atomic path
        float* cnt = (float*)d_ws;
        float* h   = (float*)((char*)d_ws + (1 << 18));
        float* msg = (float*)d_out;
        int gemmBlocks = (N + 15) / 16;

        hipMemsetAsync(cnt, 0, (size_t)N * sizeof(float), stream);
        degree_kernel<<<edgeBlocks, 256, 0, stream>>>(dst, cnt, E);

        hipMemsetAsync(msg, 0, featBytes, stream);
        scatter_kernel<<<(E * 64 + 255) / 256, 256, 0, stream>>>(x, src, dst, msg, E);
        gemm_kernel<true><<<gemmBlocks, 256, 0, stream>>>(msg, cnt, x, Wl0, Wr0, b0, h, N);

        hipMemsetAsync(msg, 0, featBytes, stream);
        scatter_kernel<<<(E * 64 + 255) / 256, 256, 0, stream>>>(h, src, dst, msg, E);
        gemm_kernel<false><<<gemmBlocks, 256, 0, stream>>>(msg, cnt, h, Wl1, Wr1, b1, msg, N);
    }
}

// Round 7
// 199.305 us; speedup vs baseline: 1.2130x; 1.2130x over previous
//
#include <hip/hip_runtime.h>

#define FDIM 128
#define NGRP 8

typedef __attribute__((ext_vector_type(4))) float f32x4;
typedef __attribute__((ext_vector_type(8))) short s16x8;
typedef __attribute__((ext_vector_type(4))) short s16x4;

__device__ inline unsigned short f2bf(float f) {      // RNE f32->bf16
    unsigned u = __builtin_bit_cast(unsigned, f);
    u += 0x7FFFu + ((u >> 16) & 1u);
    return (unsigned short)(u >> 16);
}
__device__ inline float bflo(unsigned u) { return __builtin_bit_cast(float, u << 16); }
__device__ inline float bfhi(unsigned u) { return __builtin_bit_cast(float, u & 0xFFFF0000u); }

// =============== XCD-sharded CSR build ===============
// Everything indexed [(bid&7)*N + node]: each group-g slice is a contiguous
// region (incl. its atomic cursor lines) touched by one XCD-residue class only.

__global__ void hist8_kernel(const int* __restrict__ dst, int* __restrict__ degg, int E, int N) {
    int e = blockIdx.x * blockDim.x + threadIdx.x;
    if (e < E) atomicAdd(&degg[(blockIdx.x & 7) * N + dst[e]], 1);
}

// flat exclusive scan over M=8N elems, 4 elems/thread (1024/block)
__global__ void scanA1_kernel(const int* __restrict__ in, int* __restrict__ out,
                              int* __restrict__ bsum, int M) {
    __shared__ int s[256];
    int base = blockIdx.x * 1024 + threadIdx.x * 4;
    int4 v = make_int4(0, 0, 0, 0);
    if (base + 3 < M) v = *reinterpret_cast<const int4*>(in + base);
    else {
        if (base + 0 < M) v.x = in[base + 0];
        if (base + 1 < M) v.y = in[base + 1];
        if (base + 2 < M) v.z = in[base + 2];
        if (base + 3 < M) v.w = in[base + 3];
    }
    int tsum = v.x + v.y + v.z + v.w;
    s[threadIdx.x] = tsum;
    __syncthreads();
    for (int off = 1; off < 256; off <<= 1) {
        int t = (threadIdx.x >= off) ? s[threadIdx.x - off] : 0;
        __syncthreads();
        s[threadIdx.x] += t;
        __syncthreads();
    }
    int excl = s[threadIdx.x] - tsum;
    int4 o;
    o.x = excl; o.y = excl + v.x; o.z = o.y + v.y; o.w = o.z + v.z;
    if (base + 3 < M) *reinterpret_cast<int4*>(out + base) = o;
    else {
        if (base + 0 < M) out[base + 0] = o.x;
        if (base + 1 < M) out[base + 1] = o.y;
        if (base + 2 < M) out[base + 2] = o.z;
    }
    if (threadIdx.x == 255) bsum[blockIdx.x] = s[255];
}

__global__ void scanA2_kernel(int* __restrict__ bsum, int nb) {
    __shared__ int s[512];
    int v = (threadIdx.x < (unsigned)nb) ? bsum[threadIdx.x] : 0;
    s[threadIdx.x] = v;
    __syncthreads();
    for (int off = 1; off < 512; off <<= 1) {
        int t = (threadIdx.x >= off) ? s[threadIdx.x - off] : 0;
        __syncthreads();
        s[threadIdx.x] += t;
        __syncthreads();
    }
    if (threadIdx.x < (unsigned)nb) bsum[threadIdx.x] = s[threadIdx.x] - v;
}

// add block offsets; duplicate into cursor; set off[M]=E
__global__ void scanA3_kernel(int* __restrict__ off, int* __restrict__ cursor,
                              const int* __restrict__ bsum, int M, int E) {
    int base = blockIdx.x * 1024 + threadIdx.x * 4;
    int b = bsum[blockIdx.x];
    if (base + 3 < M) {
        int4 v = *reinterpret_cast<const int4*>(off + base);
        v.x += b; v.y += b; v.z += b; v.w += b;
        *reinterpret_cast<int4*>(off + base) = v;
        *reinterpret_cast<int4*>(cursor + base) = v;
    } else {
#pragma unroll
        for (int j = 0; j < 4; ++j)
            if (base + j < M) { int t = off[base + j] + b; off[base + j] = t; cursor[base + j] = t; }
    }
    if (base == 0) off[M] = E;
}

// rp[i] = sum_g off[g*N+i] - sum_g off[g*N]   (constant-base trick, no 2nd scan)
__global__ void rp_kernel(const int* __restrict__ off, int* __restrict__ rp, int N, int E) {
    __shared__ int S0;
    if (threadIdx.x == 0) {
        int s = 0;
#pragma unroll
        for (int g = 0; g < NGRP; ++g) s += off[g * N];
        S0 = s;
    }
    __syncthreads();
    int i = blockIdx.x * 256 + threadIdx.x;
    if (i < N) {
        int s = 0;
#pragma unroll
        for (int g = 0; g < NGRP; ++g) s += off[g * N + i];
        rp[i] = s - S0;
    } else if (i == N) {
        rp[N] = E;
    }
}

__global__ void fill8_kernel(const int* __restrict__ src, const int* __restrict__ dst,
                             int* __restrict__ cursor, int* __restrict__ eidt, int E, int N) {
    int e = blockIdx.x * blockDim.x + threadIdx.x;
    if (e < E) {
        int p = atomicAdd(&cursor[(blockIdx.x & 7) * N + dst[e]], 1);
        eidt[p] = src[e];
    }
}

// per-node: concatenate the 8 group-runs into the final dense eid
__global__ void merge_kernel(const int* __restrict__ off, const int* __restrict__ eidt,
                             const int* __restrict__ rp, int* __restrict__ eid, int N) {
    int i = blockIdx.x * 256 + threadIdx.x;
    if (i >= N) return;
    int dp = rp[i];
#pragma unroll
    for (int g = 0; g < NGRP; ++g) {
        int b = off[g * N + i];
        int e2 = off[g * N + i + 1];   // i=N-1: = base of next group / off[8N]=E — correct run end
        for (int k = b; k < e2; ++k) eid[dp++] = eidt[k];
    }
}

// ======================= bf16 prep =======================
__global__ void prep_x_kernel(const float* __restrict__ x, short* __restrict__ xb, int n4) {
    int i = blockIdx.x * blockDim.x + threadIdx.x;
    if (i < n4) {
        float4 v = reinterpret_cast<const float4*>(x)[i];
        s16x4 o;
        o[0] = (short)f2bf(v.x); o[1] = (short)f2bf(v.y);
        o[2] = (short)f2bf(v.z); o[3] = (short)f2bf(v.w);
        reinterpret_cast<s16x4*>(xb)[i] = o;
    }
}

__global__ void prep_w_kernel(const float* __restrict__ Wl0, const float* __restrict__ Wr0,
                              const float* __restrict__ Wl1, const float* __restrict__ Wr1,
                              short* __restrict__ Wt0, short* __restrict__ Wt1) {
    int g = blockIdx.x * blockDim.x + threadIdx.x;   // [0, 65536)
    int n = g & 127;
    int k = (g >> 7) & 255;
    int layer = g >> 15;
    const float* Wl = layer ? Wl1 : Wl0;
    const float* Wr = layer ? Wr1 : Wr0;
    short* Wt = layer ? Wt1 : Wt0;
    float v = (k < 128) ? Wl[k * 128 + n] : Wr[(k - 128) * 128 + n];
    Wt[n * 256 + k] = (short)f2bf(v);
}

// ============ gather v2: 4 neighbor rows per wave-instruction ============
// Wave per node. Lane = (g: neighbor slot 0..3) x (c: col chunk 0..15, cols 8c..8c+7).
// Each lane loads dwordx4 (16B) -> wave reads 4 rows x 256B = 1KB/inst.
// Cross-slot reduce via shfl_xor(16), shfl_xor(32); lanes g==0 write the row.
#define ACC8(v) { a[0]+=bflo(v.x); a[1]+=bfhi(v.x); a[2]+=bflo(v.y); a[3]+=bfhi(v.y); \
                  a[4]+=bflo(v.z); a[5]+=bfhi(v.z); a[6]+=bflo(v.w); a[7]+=bfhi(v.w); }

__global__ void gather_kernel(const short* __restrict__ X, const int* __restrict__ rp,
                              const int* __restrict__ eid, short* __restrict__ mb, int N) {
    int node = blockIdx.x * (blockDim.x >> 6) + (threadIdx.x >> 6);
    int lane = threadIdx.x & 63;
    int g = lane >> 4;
    int c = lane & 15;
    if (node >= N) return;
    int beg = rp[node], end = rp[node + 1];
    float a[8];
#pragma unroll
    for (int j = 0; j < 8; ++j) a[j] = 0.0f;

    int k = beg;
    for (; k + 8 <= end; k += 8) {           // two independent 4-row loads in flight
        int s0 = eid[k + g];
        int s1 = eid[k + 4 + g];
        uint4 v0 = *reinterpret_cast<const uint4*>(X + (size_t)s0 * FDIM + c * 8);
        uint4 v1 = *reinterpret_cast<const uint4*>(X + (size_t)s1 * FDIM + c * 8);
        ACC8(v0);
        ACC8(v1);
    }
    if (k + 4 <= end) {
        int s0 = eid[k + g];
        uint4 v0 = *reinterpret_cast<const uint4*>(X + (size_t)s0 * FDIM + c * 8);
        ACC8(v0);
        k += 4;
    }
    int rem = end - k;                        // 0..3
    if (g < rem) {
        int s0 = eid[k + g];
        uint4 v0 = *reinterpret_cast<const uint4*>(X + (size_t)s0 * FDIM + c * 8);
        ACC8(v0);
    }

#pragma unroll
    for (int j = 0; j < 8; ++j) a[j] += __shfl_xor(a[j], 16);
#pragma unroll
    for (int j = 0; j < 8; ++j) a[j] += __shfl_xor(a[j], 32);

    if (g == 0) {
        float inv = (end > beg) ? 1.0f / (float)(end - beg) : 0.0f;
        uint4 o;
        o.x = (unsigned)f2bf(a[0] * inv) | ((unsigned)f2bf(a[1] * inv) << 16);
        o.y = (unsigned)f2bf(a[2] * inv) | ((unsigned)f2bf(a[3] * inv) << 16);
        o.z = (unsigned)f2bf(a[4] * inv) | ((unsigned)f2bf(a[5] * inv) << 16);
        o.w = (unsigned)f2bf(a[6] * inv) | ((unsigned)f2bf(a[7] * inv) << 16);
        *reinterpret_cast<uint4*>(mb + (size_t)node * FDIM + c * 8) = o;
    }
}

// ===================== MFMA GEMM: out = [mean|x] @ [Wl;Wr] + b (R4-proven) ============
template <bool RELU, bool OUTF32>
__global__ __launch_bounds__(256, 2)
void gemm_mfma_kernel(const short* __restrict__ Am, const short* Ax,
                      const short* __restrict__ Wt, const float* __restrict__ bias,
                      float* outf, short* outb, int n) {
    __shared__ short A_lds[64 * 256];   // 32 KB
    const int tid = threadIdx.x;
    const int w = tid >> 6, l = tid & 63;
    const int row0 = blockIdx.x * 64;

    s16x8 bfr[8][2];
    {
        const short* wb = Wt + ((32 * w + (l & 15)) * 256 + 8 * (l >> 4));
#pragma unroll
        for (int kc = 0; kc < 8; ++kc)
#pragma unroll
            for (int cf = 0; cf < 2; ++cf)
                bfr[kc][cf] = *reinterpret_cast<const s16x8*>(wb + cf * 16 * 256 + kc * 32);
    }

#pragma unroll
    for (int i = 0; i < 8; ++i) {
        int c = tid + 256 * i;          // [0, 2048)
        int r = c >> 5;
        int ck = c & 31;
        int row = row0 + r;
        s16x8 v;
        if (row < n) {
            const short* sp = (ck < 16) ? (Am + (size_t)row * FDIM + ck * 8)
                                        : (Ax + (size_t)row * FDIM + (ck - 16) * 8);
            v = *reinterpret_cast<const s16x8*>(sp);
        } else {
#pragma unroll
            for (int j = 0; j < 8; ++j) v[j] = 0;
        }
        int byte = r * 512 + ((ck * 16) ^ ((r & 7) << 4));
        *reinterpret_cast<s16x8*>(reinterpret_cast<char*>(A_lds) + byte) = v;
    }
    __syncthreads();

    f32x4 acc[4][2];
    {
        float b0 = bias[32 * w + (l & 15)];
        float b1 = bias[32 * w + 16 + (l & 15)];
#pragma unroll
        for (int rf = 0; rf < 4; ++rf)
#pragma unroll
            for (int i = 0; i < 4; ++i) { acc[rf][0][i] = b0; acc[rf][1][i] = b1; }
    }

    const int arow = l & 15;
    const int aq16 = 16 * (l >> 4);
#pragma unroll
    for (int kc = 0; kc < 8; ++kc) {
        s16x8 afr[4];
#pragma unroll
        for (int rf = 0; rf < 4; ++rf) {
            int r = 16 * rf + arow;
            int kbyte = 64 * kc + aq16;
            int byte = r * 512 + (kbyte ^ ((r & 7) << 4));
            afr[rf] = *reinterpret_cast<const s16x8*>(reinterpret_cast<const char*>(A_lds) + byte);
        }
#pragma unroll
        for (int rf = 0; rf < 4; ++rf)
#pragma unroll
            for (int cf = 0; cf < 2; ++cf)
                acc[rf][cf] = __builtin_amdgcn_mfma_f32_16x16x32_bf16(afr[rf], bfr[kc][cf], acc[rf][cf], 0, 0, 0);
    }

    const int ocol = 32 * w + (l & 15);
    const int orow = 4 * (l >> 4);
#pragma unroll
    for (int rf = 0; rf < 4; ++rf)
#pragma unroll
        for (int cf = 0; cf < 2; ++cf)
#pragma unroll
            for (int i = 0; i < 4; ++i) {
                int row = row0 + 16 * rf + orow + i;
                if (row < n) {
                    float v = acc[rf][cf][i];
                    if (RELU) v = fmaxf(v, 0.0f);
                    if (OUTF32) outf[(size_t)row * FDIM + ocol + 16 * cf] = v;
                    else        outb[(size_t)row * FDIM + ocol + 16 * cf] = (short)f2bf(v);
                }
            }
}

// ===================== fallback: atomic scatter path (R2, proven) =====================
__global__ void degree_kernel(const int* __restrict__ dst, float* __restrict__ cnt, int E) {
    int e = blockIdx.x * blockDim.x + threadIdx.x;
    if (e < E) atomicAdd(&cnt[dst[e]], 1.0f);
}

__global__ void scatter_kernel(const float* __restrict__ x, const int* __restrict__ src,
                               const int* __restrict__ dst, float* __restrict__ msg, int E) {
    int gt = blockIdx.x * blockDim.x + threadIdx.x;
    int e = gt >> 6;
    int lane = gt & 63;
    if (e >= E) return;
    int s = src[e];
    int d = dst[e];
    float2 v = reinterpret_cast<const float2*>(x + (size_t)s * FDIM)[lane];
    float* md = msg + (size_t)d * FDIM + 2 * lane;
    atomicAdd(md, v.x);
    atomicAdd(md + 1, v.y);
}

template <bool RELU>
__global__ void gemm_kernel(const float* agg, const float* cnt,
                            const float* __restrict__ xin, const float* __restrict__ Wl,
                            const float* __restrict__ Wr, const float* __restrict__ bias,
                            float* out, int n) {
    const int ROWS = 16;
    __shared__ float m_s[ROWS][FDIM];
    __shared__ float x_s[ROWS][FDIM];
    int tid = threadIdx.x;
    int row0 = blockIdx.x * ROWS;
#pragma unroll
    for (int i = 0; i < 2; ++i) {
        int idx4 = tid + i * 256;
        int r = idx4 >> 5;
        int c4 = idx4 & 31;
        int row = row0 + r;
        if (row < n) {
            float inv = cnt ? 1.0f / fmaxf(cnt[row], 1.0f) : 1.0f;
            float4 mv = reinterpret_cast<const float4*>(agg + (size_t)row * FDIM)[c4];
            float4 xv = reinterpret_cast<const float4*>(xin + (size_t)row * FDIM)[c4];
            float* mp = &m_s[r][c4 * 4];
            mp[0] = mv.x * inv; mp[1] = mv.y * inv; mp[2] = mv.z * inv; mp[3] = mv.w * inv;
            float* xp = &x_s[r][c4 * 4];
            xp[0] = xv.x; xp[1] = xv.y; xp[2] = xv.z; xp[3] = xv.w;
        }
    }
    __syncthreads();
    int j = tid & 127;
    int rh = tid >> 7;
    float acc[8];
    float bj = bias[j];
#pragma unroll
    for (int r = 0; r < 8; ++r) acc[r] = bj;
#pragma unroll 4
    for (int k = 0; k < FDIM; ++k) {
        float wl = Wl[k * FDIM + j];
        float wr = Wr[k * FDIM + j];
#pragma unroll
        for (int r = 0; r < 8; ++r)
            acc[r] += m_s[rh * 8 + r][k] * wl + x_s[rh * 8 + r][k] * wr;
    }
#pragma unroll
    for (int r = 0; r < 8; ++r) {
        int row = row0 + rh * 8 + r;
        if (row < n) {
            float v = acc[r];
            if (RELU) v = fmaxf(v, 0.0f);
            out[(size_t)row * FDIM + j] = v;
        }
    }
}

extern "C" void kernel_launch(void* const* d_in, const int* in_sizes, int n_in,
                              void* d_out, int out_size, void* d_ws, size_t ws_size,
                              hipStream_t stream) {
    const float* x   = (const float*)d_in[0];
    const int*   ei  = (const int*)d_in[1];
    const float* Wl0 = (const float*)d_in[2];
    const float* Wr0 = (const float*)d_in[3];
    const float* b0  = (const float*)d_in[4];
    const float* Wl1 = (const float*)d_in[5];
    const float* Wr1 = (const float*)d_in[6];
    const float* b1  = (const float*)d_in[7];

    int N = in_sizes[0] / FDIM;   // 50000
    int E = in_sizes[1] / 2;      // 800000
    const int* src = ei;
    const int* dst = ei + E;

    size_t featBytes  = (size_t)N * FDIM * sizeof(float);   // 25.6 MB
    size_t featBytesB = (size_t)N * FDIM * sizeof(short);   // 12.8 MB
    int edgeBlocks = (E + 255) / 256;                       // 3125
    int M = NGRP * N;                                       // 400000
    int blocksA = (M + 1023) / 1024;                        // 391

    // ---- workspace layout (29.1 MB; CSR temps overlay the dead mb region) ----
    const size_t o_bsum = 0x0;                    // 4 KB (blocksA ints)
    const size_t o_rp   = 0x1000;                 // N+1 ints
    const size_t o_wt0  = 0x33000;                // 64 KB
    const size_t o_wt1  = 0x43000;                // 64 KB
    const size_t o_eid  = 0x53000;                // E ints (3.2 MB)
    const size_t o_xb   = 0x361000;               // N*128 bf16 (x, then h in-place)
    const size_t o_mb   = o_xb + featBytesB;      // N*128 bf16 (mean), overlays CSR temps
    const size_t need   = o_mb + featBytesB;      // ~29.14 MB
    // CSR temps inside mb region (dead until gather; all fully written before read):
    const size_t s_degg = o_mb + 0x0;             // 8N ints (1.6 MB)
    const size_t s_off  = o_mb + 0x187000;        // 8N+1 ints
    const size_t s_cur  = o_mb + 0x30E000;        // 8N ints
    const size_t s_eidt = o_mb + 0x495000;        // E ints (3.2 MB) — ends at +8.0 MB < 12.8 MB

    if (ws_size >= need) {
        int*   bsum   = (int*)((char*)d_ws + o_bsum);
        int*   rp     = (int*)((char*)d_ws + o_rp);
        short* Wt0    = (short*)((char*)d_ws + o_wt0);
        short* Wt1    = (short*)((char*)d_ws + o_wt1);
        int*   eid    = (int*)((char*)d_ws + o_eid);
        short* xb     = (short*)((char*)d_ws + o_xb);
        short* mb     = (short*)((char*)d_ws + o_mb);
        int*   degg   = (int*)((char*)d_ws + s_degg);
        int*   off    = (int*)((char*)d_ws + s_off);
        int*   cursor = (int*)((char*)d_ws + s_cur);
        int*   eidt   = (int*)((char*)d_ws + s_eidt);
        float* outF   = (float*)d_out;

        // XCD-sharded CSR build
        hipMemsetAsync(degg, 0, (size_t)M * sizeof(int), stream);
        hist8_kernel<<<edgeBlocks, 256, 0, stream>>>(dst, degg, E, N);
        scanA1_kernel<<<blocksA, 256, 0, stream>>>(degg, off, bsum, M);
        scanA2_kernel<<<1, 512, 0, stream>>>(bsum, blocksA);
        scanA3_kernel<<<blocksA, 256, 0, stream>>>(off, cursor, bsum, M, E);
        rp_kernel<<<(N + 256) / 256, 256, 0, stream>>>(off, rp, N, E);
        fill8_kernel<<<edgeBlocks, 256, 0, stream>>>(src, dst, cursor, eidt, E, N);
        merge_kernel<<<(N + 255) / 256, 256, 0, stream>>>(off, eidt, rp, eid, N);

        // bf16 prep
        prep_w_kernel<<<256, 256, 0, stream>>>(Wl0, Wr0, Wl1, Wr1, Wt0, Wt1);
        prep_x_kernel<<<(N * FDIM / 4 + 255) / 256, 256, 0, stream>>>(x, xb, N * FDIM / 4);

        int gatherBlocks = (N + 3) / 4;
        int gemmBlocks   = (N + 63) / 64;
        // layer 0: h(bf16, in-place over xb) = relu([mean|x] @ Wcat0 + b0)
        gather_kernel<<<gatherBlocks, 256, 0, stream>>>(xb, rp, eid, mb, N);
        gemm_mfma_kernel<true, false><<<gemmBlocks, 256, 0, stream>>>(mb, xb, Wt0, b0, nullptr, xb, N);
        // layer 1: out(f32) = [mean(h)|h] @ Wcat1 + b1
        gather_kernel<<<gatherBlocks, 256, 0, stream>>>(xb, rp, eid, mb, N);
        gemm_mfma_kernel<false, true><<<gemmBlocks, 256, 0, stream>>>(mb, xb, Wt1, b1, outF, nullptr, N);
    } else {
        // fallback: proven atomic path
        float* cnt = (float*)d_ws;
        float* h   = (float*)((char*)d_ws + (1 << 18));
        float* msg = (float*)d_out;
        int gemmBlocks = (N + 15) / 16;

        hipMemsetAsync(cnt, 0, (size_t)N * sizeof(float), stream);
        degree_kernel<<<edgeBlocks, 256, 0, stream>>>(dst, cnt, E);

        hipMemsetAsync(msg, 0, featBytes, stream);
        scatter_kernel<<<(E * 64 + 255) / 256, 256, 0, stream>>>(x, src, dst, msg, E);
        gemm_kernel<true><<<gemmBlocks, 256, 0, stream>>>(msg, cnt, x, Wl0, Wr0, b0, h, N);

        hipMemsetAsync(msg, 0, featBytes, stream);
        scatter_kernel<<<(E * 64 + 255) / 256, 256, 0, stream>>>(h, src, dst, msg, E);
        gemm_kernel<false><<<gemmBlocks, 256, 0, stream>>>(msg, cnt, h, Wl1, Wr1, b1, msg, N);
    }
}

// Round 8
// 198.899 us; speedup vs baseline: 1.2155x; 1.0020x over previous
//
#include <hip/hip_runtime.h>

#define FDIM 128
#define NGRP 8

typedef __attribute__((ext_vector_type(4))) float f32x4;
typedef __attribute__((ext_vector_type(8))) short s16x8;
typedef __attribute__((ext_vector_type(4))) short s16x4;

__device__ inline unsigned short f2bf(float f) {      // RNE f32->bf16
    unsigned u = __builtin_bit_cast(unsigned, f);
    u += 0x7FFFu + ((u >> 16) & 1u);
    return (unsigned short)(u >> 16);
}
__device__ inline float bflo(unsigned u) { return __builtin_bit_cast(float, u << 16); }
__device__ inline float bfhi(unsigned u) { return __builtin_bit_cast(float, u & 0xFFFF0000u); }

// =============== custom zero (runtime fillBuffer is latency-bound: 41us for 1.6MB) =====
__global__ void zero_kernel(int4* __restrict__ p, int n4) {
    int i = blockIdx.x * blockDim.x + threadIdx.x;
    if (i < n4) p[i] = make_int4(0, 0, 0, 0);
}

// =============== XCD-sharded CSR build (R7-proven) ===============
// Everything indexed [(bid&7)*N + node]: each group-g slice is a contiguous
// region (incl. its atomic cursor lines) touched by one XCD-residue class only.

__global__ void hist8_kernel(const int* __restrict__ dst, int* __restrict__ degg, int E, int N) {
    int e = blockIdx.x * blockDim.x + threadIdx.x;
    if (e < E) atomicAdd(&degg[(blockIdx.x & 7) * N + dst[e]], 1);
}

// flat exclusive scan over M=8N elems, 4 elems/thread (1024/block)
__global__ void scanA1_kernel(const int* __restrict__ in, int* __restrict__ out,
                              int* __restrict__ bsum, int M) {
    __shared__ int s[256];
    int base = blockIdx.x * 1024 + threadIdx.x * 4;
    int4 v = make_int4(0, 0, 0, 0);
    if (base + 3 < M) v = *reinterpret_cast<const int4*>(in + base);
    else {
        if (base + 0 < M) v.x = in[base + 0];
        if (base + 1 < M) v.y = in[base + 1];
        if (base + 2 < M) v.z = in[base + 2];
        if (base + 3 < M) v.w = in[base + 3];
    }
    int tsum = v.x + v.y + v.z + v.w;
    s[threadIdx.x] = tsum;
    __syncthreads();
    for (int off = 1; off < 256; off <<= 1) {
        int t = (threadIdx.x >= off) ? s[threadIdx.x - off] : 0;
        __syncthreads();
        s[threadIdx.x] += t;
        __syncthreads();
    }
    int excl = s[threadIdx.x] - tsum;
    int4 o;
    o.x = excl; o.y = excl + v.x; o.z = o.y + v.y; o.w = o.z + v.z;
    if (base + 3 < M) *reinterpret_cast<int4*>(out + base) = o;
    else {
        if (base + 0 < M) out[base + 0] = o.x;
        if (base + 1 < M) out[base + 1] = o.y;
        if (base + 2 < M) out[base + 2] = o.z;
    }
    if (threadIdx.x == 255) bsum[blockIdx.x] = s[255];
}

__global__ void scanA2_kernel(int* __restrict__ bsum, int nb) {
    __shared__ int s[512];
    int v = (threadIdx.x < (unsigned)nb) ? bsum[threadIdx.x] : 0;
    s[threadIdx.x] = v;
    __syncthreads();
    for (int off = 1; off < 512; off <<= 1) {
        int t = (threadIdx.x >= off) ? s[threadIdx.x - off] : 0;
        __syncthreads();
        s[threadIdx.x] += t;
        __syncthreads();
    }
    if (threadIdx.x < (unsigned)nb) bsum[threadIdx.x] = s[threadIdx.x] - v;
}

// add block offsets; duplicate into cursor; set off[M]=E
__global__ void scanA3_kernel(int* __restrict__ off, int* __restrict__ cursor,
                              const int* __restrict__ bsum, int M, int E) {
    int base = blockIdx.x * 1024 + threadIdx.x * 4;
    int b = bsum[blockIdx.x];
    if (base + 3 < M) {
        int4 v = *reinterpret_cast<const int4*>(off + base);
        v.x += b; v.y += b; v.z += b; v.w += b;
        *reinterpret_cast<int4*>(off + base) = v;
        *reinterpret_cast<int4*>(cursor + base) = v;
    } else {
#pragma unroll
        for (int j = 0; j < 4; ++j)
            if (base + j < M) { int t = off[base + j] + b; off[base + j] = t; cursor[base + j] = t; }
    }
    if (base == 0) off[M] = E;
}

// rp[i] = sum_g off[g*N+i] - sum_g off[g*N]   (constant-base trick, no 2nd scan)
__global__ void rp_kernel(const int* __restrict__ off, int* __restrict__ rp, int N, int E) {
    __shared__ int S0;
    if (threadIdx.x == 0) {
        int s = 0;
#pragma unroll
        for (int g = 0; g < NGRP; ++g) s += off[g * N];
        S0 = s;
    }
    __syncthreads();
    int i = blockIdx.x * 256 + threadIdx.x;
    if (i < N) {
        int s = 0;
#pragma unroll
        for (int g = 0; g < NGRP; ++g) s += off[g * N + i];
        rp[i] = s - S0;
    } else if (i == N) {
        rp[N] = E;
    }
}

__global__ void fill8_kernel(const int* __restrict__ src, const int* __restrict__ dst,
                             int* __restrict__ cursor, int* __restrict__ eidt, int E, int N) {
    int e = blockIdx.x * blockDim.x + threadIdx.x;
    if (e < E) {
        int p = atomicAdd(&cursor[(blockIdx.x & 7) * N + dst[e]], 1);
        eidt[p] = src[e];
    }
}

// per-node: concatenate the 8 group-runs into the final dense eid
__global__ void merge_kernel(const int* __restrict__ off, const int* __restrict__ eidt,
                             const int* __restrict__ rp, int* __restrict__ eid, int N) {
    int i = blockIdx.x * 256 + threadIdx.x;
    if (i >= N) return;
    int dp = rp[i];
#pragma unroll
    for (int g = 0; g < NGRP; ++g) {
        int b = off[g * N + i];
        int e2 = off[g * N + i + 1];
        for (int k = b; k < e2; ++k) eid[dp++] = eidt[k];
    }
}

// ======================= bf16 prep =======================
__global__ void prep_x_kernel(const float* __restrict__ x, short* __restrict__ xb, int n4) {
    int i = blockIdx.x * blockDim.x + threadIdx.x;
    if (i < n4) {
        float4 v = reinterpret_cast<const float4*>(x)[i];
        s16x4 o;
        o[0] = (short)f2bf(v.x); o[1] = (short)f2bf(v.y);
        o[2] = (short)f2bf(v.z); o[3] = (short)f2bf(v.w);
        reinterpret_cast<s16x4*>(xb)[i] = o;
    }
}

__global__ void prep_w_kernel(const float* __restrict__ Wl0, const float* __restrict__ Wr0,
                              const float* __restrict__ Wl1, const float* __restrict__ Wr1,
                              short* __restrict__ Wt0, short* __restrict__ Wt1) {
    int g = blockIdx.x * blockDim.x + threadIdx.x;   // [0, 65536)
    int n = g & 127;
    int k = (g >> 7) & 255;
    int layer = g >> 15;
    const float* Wl = layer ? Wl1 : Wl0;
    const float* Wr = layer ? Wr1 : Wr0;
    short* Wt = layer ? Wt1 : Wt0;
    float v = (k < 128) ? Wl[k * 128 + n] : Wr[(k - 128) * 128 + n];
    Wt[n * 256 + k] = (short)f2bf(v);
}

// ============ gather v2: 4 neighbor rows per wave-instruction (R7-proven) ============
#define ACC8(v) { a[0]+=bflo(v.x); a[1]+=bfhi(v.x); a[2]+=bflo(v.y); a[3]+=bfhi(v.y); \
                  a[4]+=bflo(v.z); a[5]+=bfhi(v.z); a[6]+=bflo(v.w); a[7]+=bfhi(v.w); }

__global__ void gather_kernel(const short* __restrict__ X, const int* __restrict__ rp,
                              const int* __restrict__ eid, short* __restrict__ mb, int N) {
    int node = blockIdx.x * (blockDim.x >> 6) + (threadIdx.x >> 6);
    int lane = threadIdx.x & 63;
    int g = lane >> 4;
    int c = lane & 15;
    if (node >= N) return;
    int beg = rp[node], end = rp[node + 1];
    float a[8];
#pragma unroll
    for (int j = 0; j < 8; ++j) a[j] = 0.0f;

    int k = beg;
    for (; k + 8 <= end; k += 8) {
        int s0 = eid[k + g];
        int s1 = eid[k + 4 + g];
        uint4 v0 = *reinterpret_cast<const uint4*>(X + (size_t)s0 * FDIM + c * 8);
        uint4 v1 = *reinterpret_cast<const uint4*>(X + (size_t)s1 * FDIM + c * 8);
        ACC8(v0);
        ACC8(v1);
    }
    if (k + 4 <= end) {
        int s0 = eid[k + g];
        uint4 v0 = *reinterpret_cast<const uint4*>(X + (size_t)s0 * FDIM + c * 8);
        ACC8(v0);
        k += 4;
    }
    int rem = end - k;                        // 0..3
    if (g < rem) {
        int s0 = eid[k + g];
        uint4 v0 = *reinterpret_cast<const uint4*>(X + (size_t)s0 * FDIM + c * 8);
        ACC8(v0);
    }

#pragma unroll
    for (int j = 0; j < 8; ++j) a[j] += __shfl_xor(a[j], 16);
#pragma unroll
    for (int j = 0; j < 8; ++j) a[j] += __shfl_xor(a[j], 32);

    if (g == 0) {
        float inv = (end > beg) ? 1.0f / (float)(end - beg) : 0.0f;
        uint4 o;
        o.x = (unsigned)f2bf(a[0] * inv) | ((unsigned)f2bf(a[1] * inv) << 16);
        o.y = (unsigned)f2bf(a[2] * inv) | ((unsigned)f2bf(a[3] * inv) << 16);
        o.z = (unsigned)f2bf(a[4] * inv) | ((unsigned)f2bf(a[5] * inv) << 16);
        o.w = (unsigned)f2bf(a[6] * inv) | ((unsigned)f2bf(a[7] * inv) << 16);
        *reinterpret_cast<uint4*>(mb + (size_t)node * FDIM + c * 8) = o;
    }
}

// ===================== MFMA GEMM: out = [mean|x] @ [Wl;Wr] + b (R4-proven) ============
template <bool RELU, bool OUTF32>
__global__ __launch_bounds__(256, 2)
void gemm_mfma_kernel(const short* __restrict__ Am, const short* Ax,
                      const short* __restrict__ Wt, const float* __restrict__ bias,
                      float* outf, short* outb, int n) {
    __shared__ short A_lds[64 * 256];   // 32 KB
    const int tid = threadIdx.x;
    const int w = tid >> 6, l = tid & 63;
    const int row0 = blockIdx.x * 64;

    s16x8 bfr[8][2];
    {
        const short* wb = Wt + ((32 * w + (l & 15)) * 256 + 8 * (l >> 4));
#pragma unroll
        for (int kc = 0; kc < 8; ++kc)
#pragma unroll
            for (int cf = 0; cf < 2; ++cf)
                bfr[kc][cf] = *reinterpret_cast<const s16x8*>(wb + cf * 16 * 256 + kc * 32);
    }

#pragma unroll
    for (int i = 0; i < 8; ++i) {
        int c = tid + 256 * i;          // [0, 2048)
        int r = c >> 5;
        int ck = c & 31;
        int row = row0 + r;
        s16x8 v;
        if (row < n) {
            const short* sp = (ck < 16) ? (Am + (size_t)row * FDIM + ck * 8)
                                        : (Ax + (size_t)row * FDIM + (ck - 16) * 8);
            v = *reinterpret_cast<const s16x8*>(sp);
        } else {
#pragma unroll
            for (int j = 0; j < 8; ++j) v[j] = 0;
        }
        int byte = r * 512 + ((ck * 16) ^ ((r & 7) << 4));
        *reinterpret_cast<s16x8*>(reinterpret_cast<char*>(A_lds) + byte) = v;
    }
    __syncthreads();

    f32x4 acc[4][2];
    {
        float b0 = bias[32 * w + (l & 15)];
        float b1 = bias[32 * w + 16 + (l & 15)];
#pragma unroll
        for (int rf = 0; rf < 4; ++rf)
#pragma unroll
            for (int i = 0; i < 4; ++i) { acc[rf][0][i] = b0; acc[rf][1][i] = b1; }
    }

    const int arow = l & 15;
    const int aq16 = 16 * (l >> 4);
#pragma unroll
    for (int kc = 0; kc < 8; ++kc) {
        s16x8 afr[4];
#pragma unroll
        for (int rf = 0; rf < 4; ++rf) {
            int r = 16 * rf + arow;
            int kbyte = 64 * kc + aq16;
            int byte = r * 512 + (kbyte ^ ((r & 7) << 4));
            afr[rf] = *reinterpret_cast<const s16x8*>(reinterpret_cast<const char*>(A_lds) + byte);
        }
#pragma unroll
        for (int rf = 0; rf < 4; ++rf)
#pragma unroll
            for (int cf = 0; cf < 2; ++cf)
                acc[rf][cf] = __builtin_amdgcn_mfma_f32_16x16x32_bf16(afr[rf], bfr[kc][cf], acc[rf][cf], 0, 0, 0);
    }

    const int ocol = 32 * w + (l & 15);
    const int orow = 4 * (l >> 4);
#pragma unroll
    for (int rf = 0; rf < 4; ++rf)
#pragma unroll
        for (int cf = 0; cf < 2; ++cf)
#pragma unroll
            for (int i = 0; i < 4; ++i) {
                int row = row0 + 16 * rf + orow + i;
                if (row < n) {
                    float v = acc[rf][cf][i];
                    if (RELU) v = fmaxf(v, 0.0f);
                    if (OUTF32) outf[(size_t)row * FDIM + ocol + 16 * cf] = v;
                    else        outb[(size_t)row * FDIM + ocol + 16 * cf] = (short)f2bf(v);
                }
            }
}

// ===================== fallback: atomic scatter path (R2, proven) =====================
__global__ void degree_kernel(const int* __restrict__ dst, float* __restrict__ cnt, int E) {
    int e = blockIdx.x * blockDim.x + threadIdx.x;
    if (e < E) atomicAdd(&cnt[dst[e]], 1.0f);
}

__global__ void scatter_kernel(const float* __restrict__ x, const int* __restrict__ src,
                               const int* __restrict__ dst, float* __restrict__ msg, int E) {
    int gt = blockIdx.x * blockDim.x + threadIdx.x;
    int e = gt >> 6;
    int lane = gt & 63;
    if (e >= E) return;
    int s = src[e];
    int d = dst[e];
    float2 v = reinterpret_cast<const float2*>(x + (size_t)s * FDIM)[lane];
    float* md = msg + (size_t)d * FDIM + 2 * lane;
    atomicAdd(md, v.x);
    atomicAdd(md + 1, v.y);
}

template <bool RELU>
__global__ void gemm_kernel(const float* agg, const float* cnt,
                            const float* __restrict__ xin, const float* __restrict__ Wl,
                            const float* __restrict__ Wr, const float* __restrict__ bias,
                            float* out, int n) {
    const int ROWS = 16;
    __shared__ float m_s[ROWS][FDIM];
    __shared__ float x_s[ROWS][FDIM];
    int tid = threadIdx.x;
    int row0 = blockIdx.x * ROWS;
#pragma unroll
    for (int i = 0; i < 2; ++i) {
        int idx4 = tid + i * 256;
        int r = idx4 >> 5;
        int c4 = idx4 & 31;
        int row = row0 + r;
        if (row < n) {
            float inv = cnt ? 1.0f / fmaxf(cnt[row], 1.0f) : 1.0f;
            float4 mv = reinterpret_cast<const float4*>(agg + (size_t)row * FDIM)[c4];
            float4 xv = reinterpret_cast<const float4*>(xin + (size_t)row * FDIM)[c4];
            float* mp = &m_s[r][c4 * 4];
            mp[0] = mv.x * inv; mp[1] = mv.y * inv; mp[2] = mv.z * inv; mp[3] = mv.w * inv;
            float* xp = &x_s[r][c4 * 4];
            xp[0] = xv.x; xp[1] = xv.y; xp[2] = xv.z; xp[3] = xv.w;
        }
    }
    __syncthreads();
    int j = tid & 127;
    int rh = tid >> 7;
    float acc[8];
    float bj = bias[j];
#pragma unroll
    for (int r = 0; r < 8; ++r) acc[r] = bj;
#pragma unroll 4
    for (int k = 0; k < FDIM; ++k) {
        float wl = Wl[k * FDIM + j];
        float wr = Wr[k * FDIM + j];
#pragma unroll
        for (int r = 0; r < 8; ++r)
            acc[r] += m_s[rh * 8 + r][k] * wl + x_s[rh * 8 + r][k] * wr;
    }
#pragma unroll
    for (int r = 0; r < 8; ++r) {
        int row = row0 + rh * 8 + r;
        if (row < n) {
            float v = acc[r];
            if (RELU) v = fmaxf(v, 0.0f);
            out[(size_t)row * FDIM + j] = v;
        }
    }
}

extern "C" void kernel_launch(void* const* d_in, const int* in_sizes, int n_in,
                              void* d_out, int out_size, void* d_ws, size_t ws_size,
                              hipStream_t stream) {
    const float* x   = (const float*)d_in[0];
    const int*   ei  = (const int*)d_in[1];
    const float* Wl0 = (const float*)d_in[2];
    const float* Wr0 = (const float*)d_in[3];
    const float* b0  = (const float*)d_in[4];
    const float* Wl1 = (const float*)d_in[5];
    const float* Wr1 = (const float*)d_in[6];
    const float* b1  = (const float*)d_in[7];

    int N = in_sizes[0] / FDIM;   // 50000
    int E = in_sizes[1] / 2;      // 800000
    const int* src = ei;
    const int* dst = ei + E;

    size_t featBytes  = (size_t)N * FDIM * sizeof(float);   // 25.6 MB
    size_t featBytesB = (size_t)N * FDIM * sizeof(short);   // 12.8 MB
    int edgeBlocks = (E + 255) / 256;                       // 3125
    int M = NGRP * N;                                       // 400000
    int blocksA = (M + 1023) / 1024;                        // 391

    // ---- workspace layout (29.1 MB; CSR temps overlay the dead mb region) ----
    const size_t o_bsum = 0x0;                    // 4 KB (blocksA ints)
    const size_t o_rp   = 0x1000;                 // N+1 ints
    const size_t o_wt0  = 0x33000;                // 64 KB
    const size_t o_wt1  = 0x43000;                // 64 KB
    const size_t o_eid  = 0x53000;                // E ints (3.2 MB)
    const size_t o_xb   = 0x361000;               // N*128 bf16 (x, then h in-place)
    const size_t o_mb   = o_xb + featBytesB;      // N*128 bf16 (mean), overlays CSR temps
    const size_t need   = o_mb + featBytesB;      // ~29.14 MB
    // CSR temps inside mb region (dead until gather; all fully written before read):
    const size_t s_degg = o_mb + 0x0;             // 8N ints (1.6 MB)
    const size_t s_off  = o_mb + 0x187000;        // 8N+1 ints
    const size_t s_cur  = o_mb + 0x30E000;        // 8N ints
    const size_t s_eidt = o_mb + 0x495000;        // E ints (3.2 MB) — ends at +8.0 MB < 12.8 MB

    if (ws_size >= need) {
        int*   bsum   = (int*)((char*)d_ws + o_bsum);
        int*   rp     = (int*)((char*)d_ws + o_rp);
        short* Wt0    = (short*)((char*)d_ws + o_wt0);
        short* Wt1    = (short*)((char*)d_ws + o_wt1);
        int*   eid    = (int*)((char*)d_ws + o_eid);
        short* xb     = (short*)((char*)d_ws + o_xb);
        short* mb     = (short*)((char*)d_ws + o_mb);
        int*   degg   = (int*)((char*)d_ws + s_degg);
        int*   off    = (int*)((char*)d_ws + s_off);
        int*   cursor = (int*)((char*)d_ws + s_cur);
        int*   eidt   = (int*)((char*)d_ws + s_eidt);
        float* outF   = (float*)d_out;

        // XCD-sharded CSR build (custom zero: runtime fill took 41us for 1.6MB)
        zero_kernel<<<(M / 4 + 255) / 256, 256, 0, stream>>>((int4*)degg, M / 4);
        hist8_kernel<<<edgeBlocks, 256, 0, stream>>>(dst, degg, E, N);
        scanA1_kernel<<<blocksA, 256, 0, stream>>>(degg, off, bsum, M);
        scanA2_kernel<<<1, 512, 0, stream>>>(bsum, blocksA);
        scanA3_kernel<<<blocksA, 256, 0, stream>>>(off, cursor, bsum, M, E);
        rp_kernel<<<(N + 256) / 256, 256, 0, stream>>>(off, rp, N, E);
        fill8_kernel<<<edgeBlocks, 256, 0, stream>>>(src, dst, cursor, eidt, E, N);
        merge_kernel<<<(N + 255) / 256, 256, 0, stream>>>(off, eidt, rp, eid, N);

        // bf16 prep
        prep_w_kernel<<<256, 256, 0, stream>>>(Wl0, Wr0, Wl1, Wr1, Wt0, Wt1);
        prep_x_kernel<<<(N * FDIM / 4 + 255) / 256, 256, 0, stream>>>(x, xb, N * FDIM / 4);

        int gatherBlocks = (N + 3) / 4;
        int gemmBlocks   = (N + 63) / 64;
        // layer 0: h(bf16, in-place over xb) = relu([mean|x] @ Wcat0 + b0)
        gather_kernel<<<gatherBlocks, 256, 0, stream>>>(xb, rp, eid, mb, N);
        gemm_mfma_kernel<true, false><<<gemmBlocks, 256, 0, stream>>>(mb, xb, Wt0, b0, nullptr, xb, N);
        // layer 1: out(f32) = [mean(h)|h] @ Wcat1 + b1
        gather_kernel<<<gatherBlocks, 256, 0, stream>>>(xb, rp, eid, mb, N);
        gemm_mfma_kernel<false, true><<<gemmBlocks, 256, 0, stream>>>(mb, xb, Wt1, b1, outF, nullptr, N);
    } else {
        // fallback: proven atomic path
        float* cnt = (float*)d_ws;
        float* h   = (float*)((char*)d_ws + (1 << 18));
        float* msg = (float*)d_out;
        int gemmBlocks = (N + 15) / 16;

        hipMemsetAsync(cnt, 0, (size_t)N * sizeof(float), stream);
        degree_kernel<<<edgeBlocks, 256, 0, stream>>>(dst, cnt, E);

        hipMemsetAsync(msg, 0, featBytes, stream);
        scatter_kernel<<<(E * 64 + 255) / 256, 256, 0, stream>>>(x, src, dst, msg, E);
        gemm_kernel<true><<<gemmBlocks, 256, 0, stream>>>(msg, cnt, x, Wl0, Wr0, b0, h, N);

        hipMemsetAsync(msg, 0, featBytes, stream);
        scatter_kernel<<<(E * 64 + 255) / 256, 256, 0, stream>>>(h, src, dst, msg, E);
        gemm_kernel<false><<<gemmBlocks, 256, 0, stream>>>(msg, cnt, h, Wl1, Wr1, b1, msg, N);
    }
}

// Round 9
// 188.357 us; speedup vs baseline: 1.2835x; 1.0560x over previous
//
#include <hip/hip_runtime.h>

#define FDIM 128
#define NGRP 8

typedef __attribute__((ext_vector_type(4))) float f32x4;
typedef __attribute__((ext_vector_type(8))) short s16x8;
typedef __attribute__((ext_vector_type(4))) short s16x4;

__device__ inline unsigned short f2bf(float f) {      // RNE f32->bf16
    unsigned u = __builtin_bit_cast(unsigned, f);
    u += 0x7FFFu + ((u >> 16) & 1u);
    return (unsigned short)(u >> 16);
}
__device__ inline float bflo(unsigned u) { return __builtin_bit_cast(float, u << 16); }
__device__ inline float bfhi(unsigned u) { return __builtin_bit_cast(float, u & 0xFFFF0000u); }

// =============== prologue: zero(degg) + prep_x + prep_w in ONE kernel ===============
// blockIdx ranges: [0,ZB) zero, [ZB,ZB+XB) x->bf16, [ZB+XB,ZB+XB+WB) weight transpose.
__global__ void prologue_kernel(int4* __restrict__ degg4, int nz,
                                const float* __restrict__ x, short* __restrict__ xb, int n4x,
                                const float* __restrict__ Wl0, const float* __restrict__ Wr0,
                                const float* __restrict__ Wl1, const float* __restrict__ Wr1,
                                short* __restrict__ Wt0, short* __restrict__ Wt1,
                                int ZB, int XB) {
    int bid = blockIdx.x;
    if (bid < ZB) {
        int i = bid * 256 + threadIdx.x;
        if (i < nz) degg4[i] = make_int4(0, 0, 0, 0);
    } else if (bid < ZB + XB) {
        int i = (bid - ZB) * 256 + threadIdx.x;
        if (i < n4x) {
            float4 v = reinterpret_cast<const float4*>(x)[i];
            s16x4 o;
            o[0] = (short)f2bf(v.x); o[1] = (short)f2bf(v.y);
            o[2] = (short)f2bf(v.z); o[3] = (short)f2bf(v.w);
            reinterpret_cast<s16x4*>(xb)[i] = o;
        }
    } else {
        int g = (bid - ZB - XB) * 256 + threadIdx.x;   // [0, 65536)
        int n = g & 127;
        int k = (g >> 7) & 255;
        int layer = g >> 15;
        const float* Wl = layer ? Wl1 : Wl0;
        const float* Wr = layer ? Wr1 : Wr0;
        short* Wt = layer ? Wt1 : Wt0;
        float v = (k < 128) ? Wl[k * 128 + n] : Wr[(k - 128) * 128 + n];
        Wt[n * 256 + k] = (short)f2bf(v);
    }
}

// =============== XCD-sharded CSR build (R7-proven) ===============
__global__ void hist8_kernel(const int* __restrict__ dst, int* __restrict__ degg, int E, int N) {
    int e = blockIdx.x * blockDim.x + threadIdx.x;
    if (e < E) atomicAdd(&degg[(blockIdx.x & 7) * N + dst[e]], 1);
}

// flat exclusive scan over M=8N elems, 4 elems/thread (1024/block); block totals to bsum
__global__ void scanA1_kernel(const int* __restrict__ in, int* __restrict__ out,
                              int* __restrict__ bsum, int M) {
    __shared__ int s[256];
    int base = blockIdx.x * 1024 + threadIdx.x * 4;
    int4 v = make_int4(0, 0, 0, 0);
    if (base + 3 < M) v = *reinterpret_cast<const int4*>(in + base);
    else {
        if (base + 0 < M) v.x = in[base + 0];
        if (base + 1 < M) v.y = in[base + 1];
        if (base + 2 < M) v.z = in[base + 2];
        if (base + 3 < M) v.w = in[base + 3];
    }
    int tsum = v.x + v.y + v.z + v.w;
    s[threadIdx.x] = tsum;
    __syncthreads();
    for (int off = 1; off < 256; off <<= 1) {
        int t = (threadIdx.x >= off) ? s[threadIdx.x - off] : 0;
        __syncthreads();
        s[threadIdx.x] += t;
        __syncthreads();
    }
    int excl = s[threadIdx.x] - tsum;
    int4 o;
    o.x = excl; o.y = excl + v.x; o.z = o.y + v.y; o.w = o.z + v.z;
    if (base + 3 < M) *reinterpret_cast<int4*>(out + base) = o;
    else {
        if (base + 0 < M) out[base + 0] = o.x;
        if (base + 1 < M) out[base + 1] = o.y;
        if (base + 2 < M) out[base + 2] = o.z;
    }
    if (threadIdx.x == 255) bsum[blockIdx.x] = s[255];
}

// scanA3 v2: folds the bsum prefix-scan in (each block reduces bsum[0..bid) itself).
// Requires nb <= 512 (nb = 391 here).
__global__ void scanA3_kernel(int* __restrict__ off, int* __restrict__ cursor,
                              const int* __restrict__ bsum, int nb, int M, int E) {
    __shared__ int s[256];
    int t = threadIdx.x;
    int v = 0;
    if (t < blockIdx.x) v += bsum[t];
    if (t + 256 < blockIdx.x) v += bsum[t + 256];
    s[t] = v;
    __syncthreads();
    for (int off2 = 128; off2 > 0; off2 >>= 1) {
        if (t < off2) s[t] += s[t + off2];
        __syncthreads();
    }
    int b = s[0];   // exclusive prefix of block sums for this block

    int base = blockIdx.x * 1024 + t * 4;
    if (base + 3 < M) {
        int4 w = *reinterpret_cast<const int4*>(off + base);
        w.x += b; w.y += b; w.z += b; w.w += b;
        *reinterpret_cast<int4*>(off + base) = w;
        *reinterpret_cast<int4*>(cursor + base) = w;
    } else {
#pragma unroll
        for (int j = 0; j < 4; ++j)
            if (base + j < M) { int q = off[base + j] + b; off[base + j] = q; cursor[base + j] = q; }
    }
    if (base == 0) off[M] = E;
}

// rp[i] = sum_g off[g*N+i] - sum_g off[g*N]   (constant-base trick)
__global__ void rp_kernel(const int* __restrict__ off, int* __restrict__ rp, int N, int E) {
    __shared__ int S0;
    if (threadIdx.x == 0) {
        int s = 0;
#pragma unroll
        for (int g = 0; g < NGRP; ++g) s += off[g * N];
        S0 = s;
    }
    __syncthreads();
    int i = blockIdx.x * 256 + threadIdx.x;
    if (i < N) {
        int s = 0;
#pragma unroll
        for (int g = 0; g < NGRP; ++g) s += off[g * N + i];
        rp[i] = s - S0;
    } else if (i == N) {
        rp[N] = E;
    }
}

__global__ void fill8_kernel(const int* __restrict__ src, const int* __restrict__ dst,
                             int* __restrict__ cursor, int* __restrict__ eidt, int E, int N) {
    int e = blockIdx.x * blockDim.x + threadIdx.x;
    if (e < E) {
        int p = atomicAdd(&cursor[(blockIdx.x & 7) * N + dst[e]], 1);
        eidt[p] = src[e];
    }
}

// per-node: concatenate the 8 group-runs into the final dense eid
__global__ void merge_kernel(const int* __restrict__ off, const int* __restrict__ eidt,
                             const int* __restrict__ rp, int* __restrict__ eid, int N) {
    int i = blockIdx.x * 256 + threadIdx.x;
    if (i >= N) return;
    int dp = rp[i];
#pragma unroll
    for (int g = 0; g < NGRP; ++g) {
        int b = off[g * N + i];
        int e2 = off[g * N + i + 1];
        for (int k = b; k < e2; ++k) eid[dp++] = eidt[k];
    }
}

// ============ gather v3: 16 neighbor rows in flight per iteration ============
#define ACC8(v) { a[0]+=bflo(v.x); a[1]+=bfhi(v.x); a[2]+=bflo(v.y); a[3]+=bfhi(v.y); \
                  a[4]+=bflo(v.z); a[5]+=bfhi(v.z); a[6]+=bflo(v.w); a[7]+=bfhi(v.w); }

__global__ void gather_kernel(const short* __restrict__ X, const int* __restrict__ rp,
                              const int* __restrict__ eid, short* __restrict__ mb, int N) {
    int node = blockIdx.x * (blockDim.x >> 6) + (threadIdx.x >> 6);
    int lane = threadIdx.x & 63;
    int g = lane >> 4;
    int c = lane & 15;
    if (node >= N) return;
    int beg = rp[node], end = rp[node + 1];
    float a[8];
#pragma unroll
    for (int j = 0; j < 8; ++j) a[j] = 0.0f;

    int k = beg;
    for (; k + 16 <= end; k += 16) {          // 4 independent 4-row batches in flight
        int s0 = eid[k + g];
        int s1 = eid[k + 4 + g];
        int s2 = eid[k + 8 + g];
        int s3 = eid[k + 12 + g];
        uint4 v0 = *reinterpret_cast<const uint4*>(X + (size_t)s0 * FDIM + c * 8);
        uint4 v1 = *reinterpret_cast<const uint4*>(X + (size_t)s1 * FDIM + c * 8);
        uint4 v2 = *reinterpret_cast<const uint4*>(X + (size_t)s2 * FDIM + c * 8);
        uint4 v3 = *reinterpret_cast<const uint4*>(X + (size_t)s3 * FDIM + c * 8);
        ACC8(v0); ACC8(v1); ACC8(v2); ACC8(v3);
    }
    if (k + 8 <= end) {
        int s0 = eid[k + g];
        int s1 = eid[k + 4 + g];
        uint4 v0 = *reinterpret_cast<const uint4*>(X + (size_t)s0 * FDIM + c * 8);
        uint4 v1 = *reinterpret_cast<const uint4*>(X + (size_t)s1 * FDIM + c * 8);
        ACC8(v0); ACC8(v1);
        k += 8;
    }
    if (k + 4 <= end) {
        int s0 = eid[k + g];
        uint4 v0 = *reinterpret_cast<const uint4*>(X + (size_t)s0 * FDIM + c * 8);
        ACC8(v0);
        k += 4;
    }
    int rem = end - k;                        // 0..3
    if (g < rem) {
        int s0 = eid[k + g];
        uint4 v0 = *reinterpret_cast<const uint4*>(X + (size_t)s0 * FDIM + c * 8);
        ACC8(v0);
    }

#pragma unroll
    for (int j = 0; j < 8; ++j) a[j] += __shfl_xor(a[j], 16);
#pragma unroll
    for (int j = 0; j < 8; ++j) a[j] += __shfl_xor(a[j], 32);

    if (g == 0) {
        float inv = (end > beg) ? 1.0f / (float)(end - beg) : 0.0f;
        uint4 o;
        o.x = (unsigned)f2bf(a[0] * inv) | ((unsigned)f2bf(a[1] * inv) << 16);
        o.y = (unsigned)f2bf(a[2] * inv) | ((unsigned)f2bf(a[3] * inv) << 16);
        o.z = (unsigned)f2bf(a[4] * inv) | ((unsigned)f2bf(a[5] * inv) << 16);
        o.w = (unsigned)f2bf(a[6] * inv) | ((unsigned)f2bf(a[7] * inv) << 16);
        *reinterpret_cast<uint4*>(mb + (size_t)node * FDIM + c * 8) = o;
    }
}

// ===================== MFMA GEMM: out = [mean|x] @ [Wl;Wr] + b =====================
// (R4-proven structure; occupancy 2->3 blocks/CU for staging-latency hiding)
template <bool RELU, bool OUTF32>
__global__ __launch_bounds__(256, 3)
void gemm_mfma_kernel(const short* __restrict__ Am, const short* Ax,
                      const short* __restrict__ Wt, const float* __restrict__ bias,
                      float* outf, short* outb, int n) {
    __shared__ short A_lds[64 * 256];   // 32 KB
    const int tid = threadIdx.x;
    const int w = tid >> 6, l = tid & 63;
    const int row0 = blockIdx.x * 64;

    s16x8 bfr[8][2];
    {
        const short* wb = Wt + ((32 * w + (l & 15)) * 256 + 8 * (l >> 4));
#pragma unroll
        for (int kc = 0; kc < 8; ++kc)
#pragma unroll
            for (int cf = 0; cf < 2; ++cf)
                bfr[kc][cf] = *reinterpret_cast<const s16x8*>(wb + cf * 16 * 256 + kc * 32);
    }

#pragma unroll
    for (int i = 0; i < 8; ++i) {
        int c = tid + 256 * i;          // [0, 2048)
        int r = c >> 5;
        int ck = c & 31;
        int row = row0 + r;
        s16x8 v;
        if (row < n) {
            const short* sp = (ck < 16) ? (Am + (size_t)row * FDIM + ck * 8)
                                        : (Ax + (size_t)row * FDIM + (ck - 16) * 8);
            v = *reinterpret_cast<const s16x8*>(sp);
        } else {
#pragma unroll
            for (int j = 0; j < 8; ++j) v[j] = 0;
        }
        int byte = r * 512 + ((ck * 16) ^ ((r & 7) << 4));
        *reinterpret_cast<s16x8*>(reinterpret_cast<char*>(A_lds) + byte) = v;
    }
    __syncthreads();

    f32x4 acc[4][2];
    {
        float b0 = bias[32 * w + (l & 15)];
        float b1 = bias[32 * w + 16 + (l & 15)];
#pragma unroll
        for (int rf = 0; rf < 4; ++rf)
#pragma unroll
            for (int i = 0; i < 4; ++i) { acc[rf][0][i] = b0; acc[rf][1][i] = b1; }
    }

    const int arow = l & 15;
    const int aq16 = 16 * (l >> 4);
#pragma unroll
    for (int kc = 0; kc < 8; ++kc) {
        s16x8 afr[4];
#pragma unroll
        for (int rf = 0; rf < 4; ++rf) {
            int r = 16 * rf + arow;
            int kbyte = 64 * kc + aq16;
            int byte = r * 512 + (kbyte ^ ((r & 7) << 4));
            afr[rf] = *reinterpret_cast<const s16x8*>(reinterpret_cast<const char*>(A_lds) + byte);
        }
#pragma unroll
        for (int rf = 0; rf < 4; ++rf)
#pragma unroll
            for (int cf = 0; cf < 2; ++cf)
                acc[rf][cf] = __builtin_amdgcn_mfma_f32_16x16x32_bf16(afr[rf], bfr[kc][cf], acc[rf][cf], 0, 0, 0);
    }

    const int ocol = 32 * w + (l & 15);
    const int orow = 4 * (l >> 4);
#pragma unroll
    for (int rf = 0; rf < 4; ++rf)
#pragma unroll
        for (int cf = 0; cf < 2; ++cf)
#pragma unroll
            for (int i = 0; i < 4; ++i) {
                int row = row0 + 16 * rf + orow + i;
                if (row < n) {
                    float v = acc[rf][cf][i];
                    if (RELU) v = fmaxf(v, 0.0f);
                    if (OUTF32) outf[(size_t)row * FDIM + ocol + 16 * cf] = v;
                    else        outb[(size_t)row * FDIM + ocol + 16 * cf] = (short)f2bf(v);
                }
            }
}

// ===================== fallback: atomic scatter path (R2, proven) =====================
__global__ void degree_kernel(const int* __restrict__ dst, float* __restrict__ cnt, int E) {
    int e = blockIdx.x * blockDim.x + threadIdx.x;
    if (e < E) atomicAdd(&cnt[dst[e]], 1.0f);
}

__global__ void scatter_kernel(const float* __restrict__ x, const int* __restrict__ src,
                               const int* __restrict__ dst, float* __restrict__ msg, int E) {
    int gt = blockIdx.x * blockDim.x + threadIdx.x;
    int e = gt >> 6;
    int lane = gt & 63;
    if (e >= E) return;
    int s = src[e];
    int d = dst[e];
    float2 v = reinterpret_cast<const float2*>(x + (size_t)s * FDIM)[lane];
    float* md = msg + (size_t)d * FDIM + 2 * lane;
    atomicAdd(md, v.x);
    atomicAdd(md + 1, v.y);
}

template <bool RELU>
__global__ void gemm_kernel(const float* agg, const float* cnt,
                            const float* __restrict__ xin, const float* __restrict__ Wl,
                            const float* __restrict__ Wr, const float* __restrict__ bias,
                            float* out, int n) {
    const int ROWS = 16;
    __shared__ float m_s[ROWS][FDIM];
    __shared__ float x_s[ROWS][FDIM];
    int tid = threadIdx.x;
    int row0 = blockIdx.x * ROWS;
#pragma unroll
    for (int i = 0; i < 2; ++i) {
        int idx4 = tid + i * 256;
        int r = idx4 >> 5;
        int c4 = idx4 & 31;
        int row = row0 + r;
        if (row < n) {
            float inv = cnt ? 1.0f / fmaxf(cnt[row], 1.0f) : 1.0f;
            float4 mv = reinterpret_cast<const float4*>(agg + (size_t)row * FDIM)[c4];
            float4 xv = reinterpret_cast<const float4*>(xin + (size_t)row * FDIM)[c4];
            float* mp = &m_s[r][c4 * 4];
            mp[0] = mv.x * inv; mp[1] = mv.y * inv; mp[2] = mv.z * inv; mp[3] = mv.w * inv;
            float* xp = &x_s[r][c4 * 4];
            xp[0] = xv.x; xp[1] = xv.y; xp[2] = xv.z; xp[3] = xv.w;
        }
    }
    __syncthreads();
    int j = tid & 127;
    int rh = tid >> 7;
    float acc[8];
    float bj = bias[j];
#pragma unroll
    for (int r = 0; r < 8; ++r) acc[r] = bj;
#pragma unroll 4
    for (int k = 0; k < FDIM; ++k) {
        float wl = Wl[k * FDIM + j];
        float wr = Wr[k * FDIM + j];
#pragma unroll
        for (int r = 0; r < 8; ++r)
            acc[r] += m_s[rh * 8 + r][k] * wl + x_s[rh * 8 + r][k] * wr;
    }
#pragma unroll
    for (int r = 0; r < 8; ++r) {
        int row = row0 + rh * 8 + r;
        if (row < n) {
            float v = acc[r];
            if (RELU) v = fmaxf(v, 0.0f);
            out[(size_t)row * FDIM + j] = v;
        }
    }
}

extern "C" void kernel_launch(void* const* d_in, const int* in_sizes, int n_in,
                              void* d_out, int out_size, void* d_ws, size_t ws_size,
                              hipStream_t stream) {
    const float* x   = (const float*)d_in[0];
    const int*   ei  = (const int*)d_in[1];
    const float* Wl0 = (const float*)d_in[2];
    const float* Wr0 = (const float*)d_in[3];
    const float* b0  = (const float*)d_in[4];
    const float* Wl1 = (const float*)d_in[5];
    const float* Wr1 = (const float*)d_in[6];
    const float* b1  = (const float*)d_in[7];

    int N = in_sizes[0] / FDIM;   // 50000
    int E = in_sizes[1] / 2;      // 800000
    const int* src = ei;
    const int* dst = ei + E;

    size_t featBytes  = (size_t)N * FDIM * sizeof(float);   // 25.6 MB
    size_t featBytesB = (size_t)N * FDIM * sizeof(short);   // 12.8 MB
    int edgeBlocks = (E + 255) / 256;                       // 3125
    int M = NGRP * N;                                       // 400000
    int blocksA = (M + 1023) / 1024;                        // 391 (must be <= 512 for scanA3 v2)

    // ---- workspace layout (29.1 MB; CSR temps overlay the dead mb region) ----
    const size_t o_bsum = 0x0;                    // 4 KB
    const size_t o_rp   = 0x1000;                 // N+1 ints
    const size_t o_wt0  = 0x33000;                // 64 KB
    const size_t o_wt1  = 0x43000;                // 64 KB
    const size_t o_eid  = 0x53000;                // E ints (3.2 MB)
    const size_t o_xb   = 0x361000;               // N*128 bf16 (x, then h in-place)
    const size_t o_mb   = o_xb + featBytesB;      // N*128 bf16 (mean), overlays CSR temps
    const size_t need   = o_mb + featBytesB;      // ~29.14 MB
    const size_t s_degg = o_mb + 0x0;             // 8N ints
    const size_t s_off  = o_mb + 0x187000;        // 8N+1 ints
    const size_t s_cur  = o_mb + 0x30E000;        // 8N ints
    const size_t s_eidt = o_mb + 0x495000;        // E ints

    if (ws_size >= need && blocksA <= 512) {
        int*   bsum   = (int*)((char*)d_ws + o_bsum);
        int*   rp     = (int*)((char*)d_ws + o_rp);
        short* Wt0    = (short*)((char*)d_ws + o_wt0);
        short* Wt1    = (short*)((char*)d_ws + o_wt1);
        int*   eid    = (int*)((char*)d_ws + o_eid);
        short* xb     = (short*)((char*)d_ws + o_xb);
        short* mb     = (short*)((char*)d_ws + o_mb);
        int*   degg   = (int*)((char*)d_ws + s_degg);
        int*   off    = (int*)((char*)d_ws + s_off);
        int*   cursor = (int*)((char*)d_ws + s_cur);
        int*   eidt   = (int*)((char*)d_ws + s_eidt);
        float* outF   = (float*)d_out;

        // prologue: zero(degg) + x->bf16 + weight transpose, one kernel
        int nz  = M / 4;                          // 100000 int4
        int n4x = N * FDIM / 4;                   // 1.6M float4
        int ZB = (nz + 255) / 256;                // 391
        int XB = (n4x + 255) / 256;               // 6250
        int WB = (65536 + 255) / 256;             // 256
        prologue_kernel<<<ZB + XB + WB, 256, 0, stream>>>(
            (int4*)degg, nz, x, xb, n4x, Wl0, Wr0, Wl1, Wr1, Wt0, Wt1, ZB, XB);

        // XCD-sharded CSR build
        hist8_kernel<<<edgeBlocks, 256, 0, stream>>>(dst, degg, E, N);
        scanA1_kernel<<<blocksA, 256, 0, stream>>>(degg, off, bsum, M);
        scanA3_kernel<<<blocksA, 256, 0, stream>>>(off, cursor, bsum, blocksA, M, E);
        rp_kernel<<<(N + 256) / 256, 256, 0, stream>>>(off, rp, N, E);
        fill8_kernel<<<edgeBlocks, 256, 0, stream>>>(src, dst, cursor, eidt, E, N);
        merge_kernel<<<(N + 255) / 256, 256, 0, stream>>>(off, eidt, rp, eid, N);

        int gatherBlocks = (N + 3) / 4;
        int gemmBlocks   = (N + 63) / 64;
        // layer 0: h(bf16, in-place over xb) = relu([mean|x] @ Wcat0 + b0)
        gather_kernel<<<gatherBlocks, 256, 0, stream>>>(xb, rp, eid, mb, N);
        gemm_mfma_kernel<true, false><<<gemmBlocks, 256, 0, stream>>>(mb, xb, Wt0, b0, nullptr, xb, N);
        // layer 1: out(f32) = [mean(h)|h] @ Wcat1 + b1
        gather_kernel<<<gatherBlocks, 256, 0, stream>>>(xb, rp, eid, mb, N);
        gemm_mfma_kernel<false, true><<<gemmBlocks, 256, 0, stream>>>(mb, xb, Wt1, b1, outF, nullptr, N);
    } else {
        // fallback: proven atomic path
        float* cnt = (float*)d_ws;
        float* h   = (float*)((char*)d_ws + (1 << 18));
        float* msg = (float*)d_out;
        int gemmBlocks = (N + 15) / 16;

        hipMemsetAsync(cnt, 0, (size_t)N * sizeof(float), stream);
        degree_kernel<<<edgeBlocks, 256, 0, stream>>>(dst, cnt, E);

        hipMemsetAsync(msg, 0, featBytes, stream);
        scatter_kernel<<<(E * 64 + 255) / 256, 256, 0, stream>>>(x, src, dst, msg, E);
        gemm_kernel<true><<<gemmBlocks, 256, 0, stream>>>(msg, cnt, x, Wl0, Wr0, b0, h, N);

        hipMemsetAsync(msg, 0, featBytes, stream);
        scatter_kernel<<<(E * 64 + 255) / 256, 256, 0, stream>>>(h, src, dst, msg, E);
        gemm_kernel<false><<<gemmBlocks, 256, 0, stream>>>(msg, cnt, h, Wl1, Wr1, b1, msg, N);
    }
}